// Round 14
// baseline (556.160 us; speedup 1.0000x reference)
//
#include <hip/hip_runtime.h>

#define NN 4096
#define DIM 1024
#define HEADS 16
#define HD 64
#define SCALE 0.03125f
// SCALE * log2(e): exp(s*SCALE) == exp2(s*EXP2S)
#define EXP2S 0.04508422002778011f

typedef __attribute__((ext_vector_type(8))) short bf16x8;
typedef __attribute__((ext_vector_type(4))) short short4v;
typedef __attribute__((ext_vector_type(4))) float f32x4;
typedef __attribute__((ext_vector_type(4))) unsigned int u32x4;

__device__ __forceinline__ short f2bf(float f) {
  unsigned int x = __float_as_uint(f);
  unsigned int r = x + 0x7FFFu + ((x >> 16) & 1u);
  return (short)(r >> 16);
}
__device__ __forceinline__ float bf2f(short s) {
  return __uint_as_float(((unsigned int)(unsigned short)s) << 16);
}
// packed f32x2 -> bf16x2 (RNE), single instruction
__device__ __forceinline__ unsigned int cvtpk(float a, float b) {
  unsigned int r;
  asm("v_cvt_pk_bf16_f32 %0, %1, %2" : "=v"(r) : "v"(a), "v"(b));
  return r;
}
// 2^x via v_exp_f32
__device__ __forceinline__ float exp2x(float x) {
  float r;
  asm("v_exp_f32 %0, %1" : "=v"(r) : "v"(x));
  return r;
}

#define GLL16(gp, lp) __builtin_amdgcn_global_load_lds( \
    (const __attribute__((address_space(1))) unsigned int*)(gp), \
    (__attribute__((address_space(3))) unsigned int*)(lp), 16, 0, 0)

#define MFMA16(a, b, c) __builtin_amdgcn_mfma_f32_16x16x32_bf16(a, b, c, 0, 0, 0)

// ---------------- LayerNorm: f32 z -> bf16 normalized ----------------
__global__ __launch_bounds__(256) void ln_kernel(
    const float* __restrict__ z1, const float* __restrict__ z2,
    const float* __restrict__ g1, const float* __restrict__ be1,
    const float* __restrict__ g2, const float* __restrict__ be2,
    short* __restrict__ n1, short* __restrict__ n2) {
  int row = blockIdx.x;
  int which = blockIdx.y;
  const float* src = (which ? z2 : z1) + (size_t)row * DIM;
  const float* g  = which ? g2 : g1;
  const float* be = which ? be2 : be1;
  short* dst = (which ? n2 : n1) + (size_t)row * DIM;
  int t = threadIdx.x;
  float4 v = ((const float4*)src)[t];
  float s  = v.x + v.y + v.z + v.w;
  float s2 = v.x*v.x + v.y*v.y + v.z*v.z + v.w*v.w;
#pragma unroll
  for (int off = 32; off >= 1; off >>= 1) {
    s  += __shfl_xor(s, off);
    s2 += __shfl_xor(s2, off);
  }
  __shared__ __align__(16) float ls[8];
  int wid = t >> 6;
  if ((t & 63) == 0) { ls[wid] = s; ls[wid + 4] = s2; }
  __syncthreads();
  s  = ls[0] + ls[1] + ls[2] + ls[3];
  s2 = ls[4] + ls[5] + ls[6] + ls[7];
  float mu = s * (1.0f / DIM);
  float var = s2 * (1.0f / DIM) - mu * mu;
  float rs = rsqrtf(var + 1e-5f);
  float4 gv = ((const float4*)g)[t];
  float4 bv = ((const float4*)be)[t];
  short4v o;
  o.x = f2bf((v.x - mu) * rs * gv.x + bv.x);
  o.y = f2bf((v.y - mu) * rs * gv.y + bv.y);
  o.z = f2bf((v.z - mu) * rs * gv.z + bv.z);
  o.w = f2bf((v.w - mu) * rs * gv.w + bv.w);
  ((short4v*)dst)[t] = o;
}

// ---------------- weights f32 -> bf16 ----------------
__global__ __launch_bounds__(256) void cvt_w_kernel(
    const float* __restrict__ w0, const float* __restrict__ w1,
    const float* __restrict__ w2, const float* __restrict__ w3,
    short* __restrict__ wb) {
  int y = blockIdx.y;
  const float* src = (y == 0) ? w0 : (y == 1) ? w1 : (y == 2) ? w2 : w3;
  size_t i = (size_t)blockIdx.x * 256 + threadIdx.x;
  float4 v = ((const float4*)src)[i];
  short4v o;
  o.x = f2bf(v.x); o.y = f2bf(v.y); o.z = f2bf(v.z); o.w = f2bf(v.w);
  ((short4v*)(wb + (size_t)y * DIM * DIM))[i] = o;
}

// ---------------- batched projection GEMM (round-12 BK=32 — verified fast) ----------------
__global__ __launch_bounds__(256) void proj_kernel(
    const short* __restrict__ n1, const short* __restrict__ n2,
    const short* __restrict__ wb,
    const float* __restrict__ bq, const float* __restrict__ bk,
    const float* __restrict__ bv1, const float* __restrict__ bv2,
    short* __restrict__ q, short* __restrict__ k,
    short* __restrict__ vT, short* __restrict__ v1T) {
  int z = blockIdx.z;
  const short* A = (z == 1 || z == 2) ? n2 : n1;
  const short* B = wb + (size_t)z * DIM * DIM;
  const float* bias = (z == 0) ? bq : (z == 1) ? bk : (z == 2) ? bv1 : bv2;
  int i0 = blockIdx.y * 128, j0 = blockIdx.x * 128;
  __shared__ __align__(16) short As[128 * 32];
  __shared__ __align__(16) short Bs[128 * 32];
  int t = threadIdx.x;
  int wid = t >> 6, lane = t & 63, g = lane >> 4, l15 = lane & 15;
  int wi = (wid >> 1) * 64, wj = (wid & 1) * 64;
  f32x4 acc[4][4] = {};
  for (int kt = 0; kt < DIM; kt += 32) {
    __syncthreads();
#pragma unroll
    for (int e = 0; e < 2; ++e) {
      int lin = e * 256 + t;
      int row = lin >> 2, kc = (lin & 3) * 8;
      GLL16(A + (size_t)(i0 + row) * DIM + kt + kc, As + lin * 8);
      GLL16(B + (size_t)(j0 + row) * DIM + kt + kc, Bs + lin * 8);
    }
    __syncthreads();
    bf16x8 af[4], bfr[4];
#pragma unroll
    for (int it = 0; it < 4; ++it)
      af[it] = *(const bf16x8*)(As + (wi + it * 16 + l15) * 32 + g * 8);
#pragma unroll
    for (int jt = 0; jt < 4; ++jt)
      bfr[jt] = *(const bf16x8*)(Bs + (wj + jt * 16 + l15) * 32 + g * 8);
#pragma unroll
    for (int it = 0; it < 4; ++it)
#pragma unroll
      for (int jt = 0; jt < 4; ++jt)
        acc[it][jt] = MFMA16(af[it], bfr[jt], acc[it][jt]);
  }
  if (z < 2) {
    short* out = (z == 0) ? q : k;
#pragma unroll
    for (int jt = 0; jt < 4; ++jt) {
      int j = j0 + wj + jt * 16 + l15;
      float bj = bias[j];
#pragma unroll
      for (int it = 0; it < 4; ++it) {
        int i = i0 + wi + it * 16 + g * 4;
#pragma unroll
        for (int r = 0; r < 4; ++r)
          out[(size_t)(i + r) * DIM + j] = f2bf(acc[it][jt][r] + bj);
      }
    }
  } else {
    short* out = (z == 2) ? vT : v1T;
#pragma unroll
    for (int jt = 0; jt < 4; ++jt) {
      int j = j0 + wj + jt * 16 + l15;
      float bj = bias[j];
#pragma unroll
      for (int it = 0; it < 4; ++it) {
        int i = i0 + wi + it * 16 + g * 4;
        short4v o;
#pragma unroll
        for (int r = 0; r < 4; ++r) o[r] = f2bf(acc[it][jt][r] + bj);
        *(short4v*)(out + (size_t)j * NN + i) = o;
      }
    }
  }
}

// ============ p2zc: S^T formulation + fused v1T prescale epilogue ============
__global__ __launch_bounds__(256, 4) void p2zc_kernel(
    const short* __restrict__ q, const short* __restrict__ k,
    const short* __restrict__ vT, float* __restrict__ attn,
    float* __restrict__ zc, float* __restrict__ iSx,
    short* __restrict__ v1T) {
  int bid = (int)(blockIdx.y * gridDim.x + blockIdx.x);
  int vid = (bid & 7) * 128 + (bid >> 3);   // XCD-contiguous remap (1024 % 8 == 0)
  int h = vid >> 6;
  int nblk = vid & 63;
  int t = threadIdx.x, wid = t >> 6, lane = t & 63;
  int g = lane >> 4, l15 = lane & 15;
  int nw = nblk * 64 + wid * 16;

  const short* qp = q + (size_t)(nw + l15) * DIM + h * HD + g * 8;
  bf16x8 qb0 = *(const bf16x8*)(qp);
  bf16x8 qb1 = *(const bf16x8*)(qp + 32);

  __shared__ __align__(16) short Ks[128 * 64];   // 16 KB, xor-swizzled chunks
  __shared__ __align__(16) short Vs[64 * 128];   // 16 KB, xor-swizzled chunks
  __shared__ float lsS[64];                      // iS strip for v1 prescale
  const short* kb = k + h * HD;
  const short* vb = vT + (size_t)h * HD * NN;

  // ---- pass A: row sums of exp ----
  f32x4 Sp = {0.f, 0.f, 0.f, 0.f};
  for (int mc = 0; mc < NN; mc += 128) {
    __syncthreads();
#pragma unroll
    for (int e = 0; e < 4; ++e) {
      int L = e * 256 + t, row = L >> 3, c = L & 7;
      GLL16(kb + (size_t)(mc + row) * DIM + ((c ^ (row & 7)) * 8), Ks + L * 8);
    }
    __syncthreads();
#pragma unroll
    for (int mt = 0; mt < 8; ++mt) {
      const short* kr = Ks + (mt * 16 + l15) * 64;
      bf16x8 ka0 = *(const bf16x8*)(kr + ((g ^ (l15 & 7)) * 8));
      bf16x8 ka1 = *(const bf16x8*)(kr + (((g + 4) ^ (l15 & 7)) * 8));
      f32x4 acc = {0.f, 0.f, 0.f, 0.f};
      acc = MFMA16(ka0, qb0, acc);
      acc = MFMA16(ka1, qb1, acc);
#pragma unroll
      for (int r = 0; r < 4; ++r) Sp[r] += exp2x(acc[r] * EXP2S);
    }
  }
  float S = Sp[0] + Sp[1] + Sp[2] + Sp[3];
  S += __shfl_xor(S, 16);
  S += __shfl_xor(S, 32);
  float iS = 1.0f / S;
  if (lane < 16) {
    iSx[h * NN + nw + l15] = iS;
    lsS[wid * 16 + l15] = iS;
  }

  // ---- pass B: attn store (non-temporal) + PV ----
  float* ab = attn + (size_t)h * NN * NN;
  f32x4 azc[4] = {};
  for (int mc = 0; mc < NN; mc += 128) {
    __syncthreads();
#pragma unroll
    for (int e = 0; e < 4; ++e) {
      int L = e * 256 + t, row = L >> 3, c = L & 7;
      GLL16(kb + (size_t)(mc + row) * DIM + ((c ^ (row & 7)) * 8), Ks + L * 8);
    }
#pragma unroll
    for (int e = 0; e < 4; ++e) {
      int L = e * 256 + t, row = L >> 4, c = L & 15;
      GLL16(vb + (size_t)row * NN + mc + ((c ^ (row & 15)) * 8), Vs + L * 8);
    }
    __syncthreads();
    float p[8][4];
#pragma unroll
    for (int mt = 0; mt < 8; ++mt) {
      const short* kr = Ks + (mt * 16 + l15) * 64;
      bf16x8 ka0 = *(const bf16x8*)(kr + ((g ^ (l15 & 7)) * 8));
      bf16x8 ka1 = *(const bf16x8*)(kr + (((g + 4) ^ (l15 & 7)) * 8));
      f32x4 acc = {0.f, 0.f, 0.f, 0.f};
      acc = MFMA16(ka0, qb0, acc);
      acc = MFMA16(ka1, qb1, acc);
      f32x4 pv;
#pragma unroll
      for (int r = 0; r < 4; ++r) { pv[r] = exp2x(acc[r] * EXP2S) * iS; p[mt][r] = pv[r]; }
      __builtin_nontemporal_store(pv,
          (f32x4*)(ab + (size_t)(nw + l15) * NN + mc + mt * 16 + g * 4));
    }
#pragma unroll
    for (int km = 0; km < 4; ++km) {
      unsigned int a0p = cvtpk(p[2*km][0],   p[2*km][1]);
      unsigned int a1p = cvtpk(p[2*km][2],   p[2*km][3]);
      unsigned int b0p = cvtpk(p[2*km+1][0], p[2*km+1][1]);
      unsigned int b1p = cvtpk(p[2*km+1][2], p[2*km+1][3]);
      int s0 = ((g & 1) * 2) * 16 + l15, s1 = s0 + 16;
      bool hi = g >= 2;
      unsigned int w0a = __shfl(a0p, s0), w0b = __shfl(b0p, s0);
      unsigned int w1a = __shfl(a1p, s0), w1b = __shfl(b1p, s0);
      unsigned int w2a = __shfl(a0p, s1), w2b = __shfl(b0p, s1);
      unsigned int w3a = __shfl(a1p, s1), w3b = __shfl(b1p, s1);
      union { u32x4 u; bf16x8 s; } pw;
      pw.u[0] = hi ? w0b : w0a; pw.u[1] = hi ? w1b : w1a;
      pw.u[2] = hi ? w2b : w2a; pw.u[3] = hi ? w3b : w3a;
#pragma unroll
      for (int ct = 0; ct < 4; ++ct) {
        bf16x8 pb = *(const bf16x8*)(Vs + (ct * 16 + l15) * 128 + (((km * 4 + g) ^ l15) * 8));
        azc[ct] = MFMA16(pw.s, pb, azc[ct]);
      }
    }
  }
#pragma unroll
  for (int ct = 0; ct < 4; ++ct)
#pragma unroll
    for (int r = 0; r < 4; ++r)
      zc[(size_t)(nw + g * 4 + r) * DIM + h * HD + ct * 16 + l15] = azc[ct][r];

  // ---- epilogue: v1T prescale for this block's n-strip [base, base+64) ----
  int base = nblk * 64;
#pragma unroll
  for (int e = 0; e < 2; ++e) {
    int id = e * 256 + t;            // 512 chunks of 8 = 64 c x 8 chunks
    int c = id >> 3, ch = id & 7;
    short* p = v1T + (size_t)(h * HD + c) * NN + base + ch * 8;
    bf16x8 v = *(const bf16x8*)p;
    const float* isp = lsS + ch * 8;
    union { u32x4 u; bf16x8 s; } o;
    o.u[0] = cvtpk(bf2f(v[0]) * isp[0], bf2f(v[1]) * isp[1]);
    o.u[1] = cvtpk(bf2f(v[2]) * isp[2], bf2f(v[3]) * isp[3]);
    o.u[2] = cvtpk(bf2f(v[4]) * isp[4], bf2f(v[5]) * isp[5]);
    o.u[3] = cvtpk(bf2f(v[6]) * isp[6], bf2f(v[7]) * isp[7]);
    *(bf16x8*)p = o.s;
  }
}

// ============ czr: round-8 structure, prescaled v1 (no iS loads) ============
__global__ __launch_bounds__(256, 4) void czr_kernel(
    const short* __restrict__ q, const short* __restrict__ k,
    const short* __restrict__ v1T, float* __restrict__ cz) {
  int bid = (int)(blockIdx.y * gridDim.x + blockIdx.x);
  int vid = (bid & 7) * 128 + (bid >> 3);
  int h = vid >> 6;
  int mblk = vid & 63;
  int t = threadIdx.x, wid = t >> 6, lane = t & 63;
  int g = lane >> 4, l15 = lane & 15;
  int mw = mblk * 64 + wid * 16;

  const short* kp = k + (size_t)(mw + l15) * DIM + h * HD + g * 8;
  bf16x8 kb0 = *(const bf16x8*)(kp);
  bf16x8 kb1 = *(const bf16x8*)(kp + 32);

  __shared__ __align__(16) short Qs[128 * 64];
  __shared__ __align__(16) short V1s[64 * 128];
  const short* qb = q + h * HD;
  const short* vb = v1T + (size_t)h * HD * NN;

  f32x4 acz[4] = {};
  for (int nc = 0; nc < NN; nc += 128) {
    __syncthreads();
#pragma unroll
    for (int e = 0; e < 4; ++e) {
      int L = e * 256 + t, row = L >> 3, c = L & 7;
      GLL16(qb + (size_t)(nc + row) * DIM + ((c ^ (row & 7)) * 8), Qs + L * 8);
    }
#pragma unroll
    for (int e = 0; e < 4; ++e) {
      int L = e * 256 + t, row = L >> 4, c = L & 15;
      GLL16(vb + (size_t)row * NN + nc + ((c ^ (row & 15)) * 8), V1s + L * 8);
    }
    __syncthreads();
    float p[8][4];
#pragma unroll
    for (int nt = 0; nt < 8; ++nt) {
      const short* qr = Qs + (nt * 16 + l15) * 64;
      bf16x8 qa0 = *(const bf16x8*)(qr + ((g ^ (l15 & 7)) * 8));
      bf16x8 qa1 = *(const bf16x8*)(qr + (((g + 4) ^ (l15 & 7)) * 8));
      f32x4 acc = {0.f, 0.f, 0.f, 0.f};
      acc = MFMA16(qa0, kb0, acc);
      acc = MFMA16(qa1, kb1, acc);
#pragma unroll
      for (int r = 0; r < 4; ++r) p[nt][r] = exp2x(acc[r] * EXP2S);
    }
#pragma unroll
    for (int kn = 0; kn < 4; ++kn) {
      unsigned int a0p = cvtpk(p[2*kn][0],   p[2*kn][1]);
      unsigned int a1p = cvtpk(p[2*kn][2],   p[2*kn][3]);
      unsigned int b0p = cvtpk(p[2*kn+1][0], p[2*kn+1][1]);
      unsigned int b1p = cvtpk(p[2*kn+1][2], p[2*kn+1][3]);
      int s0 = ((g & 1) * 2) * 16 + l15, s1 = s0 + 16;
      bool hi = g >= 2;
      unsigned int w0a = __shfl(a0p, s0), w0b = __shfl(b0p, s0);
      unsigned int w1a = __shfl(a1p, s0), w1b = __shfl(b1p, s0);
      unsigned int w2a = __shfl(a0p, s1), w2b = __shfl(b0p, s1);
      unsigned int w3a = __shfl(a1p, s1), w3b = __shfl(b1p, s1);
      union { u32x4 u; bf16x8 s; } pw;
      pw.u[0] = hi ? w0b : w0a; pw.u[1] = hi ? w1b : w1a;
      pw.u[2] = hi ? w2b : w2a; pw.u[3] = hi ? w3b : w3a;
#pragma unroll
      for (int ct = 0; ct < 4; ++ct) {
        bf16x8 pb = *(const bf16x8*)(V1s + (ct * 16 + l15) * 128 + (((kn * 4 + g) ^ l15) * 8));
        acz[ct] = MFMA16(pw.s, pb, acz[ct]);
      }
    }
  }
#pragma unroll
  for (int ct = 0; ct < 4; ++ct)
#pragma unroll
    for (int r = 0; r < 4; ++r)
      cz[(size_t)(mw + g * 4 + r) * DIM + h * HD + ct * 16 + l15] = acz[ct][r];
}

extern "C" void kernel_launch(void* const* d_in, const int* in_sizes, int n_in,
                              void* d_out, int out_size, void* d_ws, size_t ws_size,
                              hipStream_t stream) {
  static const int expect[14] = {4194304, 4194304, 1048576, 1024, 1048576, 1024,
                                 1048576, 1024, 1048576, 1024, 1024, 1024, 1024, 1024};
  if (n_in != 14) return;
  for (int i = 0; i < 14; ++i) if (in_sizes[i] != expect[i]) return;
  if (out_size != 2 * NN * DIM + (size_t)HEADS * NN * NN) return;

  const float* z1  = (const float*)d_in[0];
  const float* z2  = (const float*)d_in[1];
  const float* wq  = (const float*)d_in[2];
  const float* bq  = (const float*)d_in[3];
  const float* wk  = (const float*)d_in[4];
  const float* bk  = (const float*)d_in[5];
  const float* wv1 = (const float*)d_in[6];
  const float* bv1 = (const float*)d_in[7];
  const float* wv2 = (const float*)d_in[8];
  const float* bv2 = (const float*)d_in[9];
  const float* g1  = (const float*)d_in[10];
  const float* be1 = (const float*)d_in[11];
  const float* g2  = (const float*)d_in[12];
  const float* be2 = (const float*)d_in[13];

  float* out  = (float*)d_out;
  float* zc   = out;
  float* cz   = out + (size_t)NN * DIM;
  float* attn = out + 2 * (size_t)NN * DIM;

  short* n1 = (short*)zc;
  short* n2 = (short*)cz;
  short* wb = (short*)attn;

  char* ws = (char*)d_ws;
  const size_t MB = 1024 * 1024;
  short* q   = (short*)(ws);
  short* k   = (short*)(ws + 8 * MB);
  short* vT  = (short*)(ws + 16 * MB);
  short* v1T = (short*)(ws + 24 * MB);
  float* iSx = (float*)(ws + 32 * MB);

  ln_kernel<<<dim3(NN, 2), 256, 0, stream>>>(z1, z2, g1, be1, g2, be2, n1, n2);
  cvt_w_kernel<<<dim3(DIM * DIM / 1024, 4), 256, 0, stream>>>(wq, wk, wv1, wv2, wb);
  proj_kernel<<<dim3(DIM / 128, NN / 128, 4), 256, 0, stream>>>(n1, n2, wb, bq, bk, bv1, bv2, q, k, vT, v1T);
  p2zc_kernel<<<dim3(NN / 64, HEADS), 256, 0, stream>>>(q, k, vT, attn, zc, iSx, v1T);
  czr_kernel<<<dim3(NN / 64, HEADS), 256, 0, stream>>>(q, k, v1T, cz);
}

// Round 15
// 535.769 us; speedup vs baseline: 1.0381x; 1.0381x over previous
//
#include <hip/hip_runtime.h>

#define NN 4096
#define DIM 1024
#define HEADS 16
#define HD 64
#define SCALE 0.03125f
// SCALE * log2(e): exp(s*SCALE) == exp2(s*EXP2S)
#define EXP2S 0.04508422002778011f

typedef __attribute__((ext_vector_type(8))) short bf16x8;
typedef __attribute__((ext_vector_type(4))) short short4v;
typedef __attribute__((ext_vector_type(4))) float f32x4;
typedef __attribute__((ext_vector_type(4))) unsigned int u32x4;

__device__ __forceinline__ short f2bf(float f) {
  unsigned int x = __float_as_uint(f);
  unsigned int r = x + 0x7FFFu + ((x >> 16) & 1u);
  return (short)(r >> 16);
}
__device__ __forceinline__ float bf2f(short s) {
  return __uint_as_float(((unsigned int)(unsigned short)s) << 16);
}
// packed f32x2 -> bf16x2 (RNE), single instruction
__device__ __forceinline__ unsigned int cvtpk(float a, float b) {
  unsigned int r;
  asm("v_cvt_pk_bf16_f32 %0, %1, %2" : "=v"(r) : "v"(a), "v"(b));
  return r;
}
// 2^x via v_exp_f32
__device__ __forceinline__ float exp2x(float x) {
  float r;
  asm("v_exp_f32 %0, %1" : "=v"(r) : "v"(x));
  return r;
}

#define GLL16(gp, lp) __builtin_amdgcn_global_load_lds( \
    (const __attribute__((address_space(1))) unsigned int*)(gp), \
    (__attribute__((address_space(3))) unsigned int*)(lp), 16, 0, 0)

#define MFMA16(a, b, c) __builtin_amdgcn_mfma_f32_16x16x32_bf16(a, b, c, 0, 0, 0)

// ---------------- LayerNorm: f32 z -> bf16 normalized ----------------
__global__ __launch_bounds__(256) void ln_kernel(
    const float* __restrict__ z1, const float* __restrict__ z2,
    const float* __restrict__ g1, const float* __restrict__ be1,
    const float* __restrict__ g2, const float* __restrict__ be2,
    short* __restrict__ n1, short* __restrict__ n2) {
  int row = blockIdx.x;
  int which = blockIdx.y;
  const float* src = (which ? z2 : z1) + (size_t)row * DIM;
  const float* g  = which ? g2 : g1;
  const float* be = which ? be2 : be1;
  short* dst = (which ? n2 : n1) + (size_t)row * DIM;
  int t = threadIdx.x;
  float4 v = ((const float4*)src)[t];
  float s  = v.x + v.y + v.z + v.w;
  float s2 = v.x*v.x + v.y*v.y + v.z*v.z + v.w*v.w;
#pragma unroll
  for (int off = 32; off >= 1; off >>= 1) {
    s  += __shfl_xor(s, off);
    s2 += __shfl_xor(s2, off);
  }
  __shared__ __align__(16) float ls[8];
  int wid = t >> 6;
  if ((t & 63) == 0) { ls[wid] = s; ls[wid + 4] = s2; }
  __syncthreads();
  s  = ls[0] + ls[1] + ls[2] + ls[3];
  s2 = ls[4] + ls[5] + ls[6] + ls[7];
  float mu = s * (1.0f / DIM);
  float var = s2 * (1.0f / DIM) - mu * mu;
  float rs = rsqrtf(var + 1e-5f);
  float4 gv = ((const float4*)g)[t];
  float4 bv = ((const float4*)be)[t];
  short4v o;
  o.x = f2bf((v.x - mu) * rs * gv.x + bv.x);
  o.y = f2bf((v.y - mu) * rs * gv.y + bv.y);
  o.z = f2bf((v.z - mu) * rs * gv.z + bv.z);
  o.w = f2bf((v.w - mu) * rs * gv.w + bv.w);
  ((short4v*)dst)[t] = o;
}

// ---------------- weights f32 -> bf16 ----------------
__global__ __launch_bounds__(256) void cvt_w_kernel(
    const float* __restrict__ w0, const float* __restrict__ w1,
    const float* __restrict__ w2, const float* __restrict__ w3,
    short* __restrict__ wb) {
  int y = blockIdx.y;
  const float* src = (y == 0) ? w0 : (y == 1) ? w1 : (y == 2) ? w2 : w3;
  size_t i = (size_t)blockIdx.x * 256 + threadIdx.x;
  float4 v = ((const float4*)src)[i];
  short4v o;
  o.x = f2bf(v.x); o.y = f2bf(v.y); o.z = f2bf(v.z); o.w = f2bf(v.w);
  ((short4v*)(wb + (size_t)y * DIM * DIM))[i] = o;
}

// ---------------- batched projection GEMM (round-5-verified, BK=32) ----------------
__global__ __launch_bounds__(256) void proj_kernel(
    const short* __restrict__ n1, const short* __restrict__ n2,
    const short* __restrict__ wb,
    const float* __restrict__ bq, const float* __restrict__ bk,
    const float* __restrict__ bv1, const float* __restrict__ bv2,
    short* __restrict__ q, short* __restrict__ k,
    short* __restrict__ vT, short* __restrict__ v1T) {
  int z = blockIdx.z;
  const short* A = (z == 1 || z == 2) ? n2 : n1;
  const short* B = wb + (size_t)z * DIM * DIM;
  const float* bias = (z == 0) ? bq : (z == 1) ? bk : (z == 2) ? bv1 : bv2;
  int i0 = blockIdx.y * 128, j0 = blockIdx.x * 128;
  __shared__ __align__(16) short As[128 * 32];
  __shared__ __align__(16) short Bs[128 * 32];
  int t = threadIdx.x;
  int wid = t >> 6, lane = t & 63, g = lane >> 4, l15 = lane & 15;
  int wi = (wid >> 1) * 64, wj = (wid & 1) * 64;
  f32x4 acc[4][4] = {};
  for (int kt = 0; kt < DIM; kt += 32) {
    __syncthreads();
#pragma unroll
    for (int e = 0; e < 2; ++e) {
      int lin = e * 256 + t;
      int row = lin >> 2, kc = (lin & 3) * 8;
      GLL16(A + (size_t)(i0 + row) * DIM + kt + kc, As + lin * 8);
      GLL16(B + (size_t)(j0 + row) * DIM + kt + kc, Bs + lin * 8);
    }
    __syncthreads();
    bf16x8 af[4], bfr[4];
#pragma unroll
    for (int it = 0; it < 4; ++it)
      af[it] = *(const bf16x8*)(As + (wi + it * 16 + l15) * 32 + g * 8);
#pragma unroll
    for (int jt = 0; jt < 4; ++jt)
      bfr[jt] = *(const bf16x8*)(Bs + (wj + jt * 16 + l15) * 32 + g * 8);
#pragma unroll
    for (int it = 0; it < 4; ++it)
#pragma unroll
      for (int jt = 0; jt < 4; ++jt)
        acc[it][jt] = MFMA16(af[it], bfr[jt], acc[it][jt]);
  }
  if (z < 2) {
    short* out = (z == 0) ? q : k;
#pragma unroll
    for (int jt = 0; jt < 4; ++jt) {
      int j = j0 + wj + jt * 16 + l15;
      float bj = bias[j];
#pragma unroll
      for (int it = 0; it < 4; ++it) {
        int i = i0 + wi + it * 16 + g * 4;
#pragma unroll
        for (int r = 0; r < 4; ++r)
          out[(size_t)(i + r) * DIM + j] = f2bf(acc[it][jt][r] + bj);
      }
    }
  } else {
    short* out = (z == 2) ? vT : v1T;
#pragma unroll
    for (int jt = 0; jt < 4; ++jt) {
      int j = j0 + wj + jt * 16 + l15;
      float bj = bias[j];
#pragma unroll
      for (int it = 0; it < 4; ++it) {
        int i = i0 + wi + it * 16 + g * 4;
        short4v o;
#pragma unroll
        for (int r = 0; r < 4; ++r) o[r] = f2bf(acc[it][jt][r] + bj);
        *(short4v*)(out + (size_t)j * NN + i) = o;
      }
    }
  }
}

// ============ p2zc: S^T formulation, LDS-staged K/V, cvt_pk repack, nt attn stores ============
__global__ __launch_bounds__(256, 4) void p2zc_kernel(
    const short* __restrict__ q, const short* __restrict__ k,
    const short* __restrict__ vT, float* __restrict__ attn,
    float* __restrict__ zc, float* __restrict__ iSx) {
  int bid = (int)(blockIdx.y * gridDim.x + blockIdx.x);
  int vid = (bid & 7) * 128 + (bid >> 3);   // XCD-contiguous remap (1024 % 8 == 0)
  int h = vid >> 6;
  int nblk = vid & 63;
  int t = threadIdx.x, wid = t >> 6, lane = t & 63;
  int g = lane >> 4, l15 = lane & 15;
  int nw = nblk * 64 + wid * 16;

  const short* qp = q + (size_t)(nw + l15) * DIM + h * HD + g * 8;
  bf16x8 qb0 = *(const bf16x8*)(qp);
  bf16x8 qb1 = *(const bf16x8*)(qp + 32);

  __shared__ __align__(16) short Ks[128 * 64];   // 16 KB, xor-swizzled chunks
  __shared__ __align__(16) short Vs[64 * 128];   // 16 KB, xor-swizzled chunks
  const short* kb = k + h * HD;
  const short* vb = vT + (size_t)h * HD * NN;

  // ---- pass A: row sums of exp ----
  f32x4 Sp = {0.f, 0.f, 0.f, 0.f};
  for (int mc = 0; mc < NN; mc += 128) {
    __syncthreads();
#pragma unroll
    for (int e = 0; e < 4; ++e) {
      int L = e * 256 + t, row = L >> 3, c = L & 7;
      GLL16(kb + (size_t)(mc + row) * DIM + ((c ^ (row & 7)) * 8), Ks + L * 8);
    }
    __syncthreads();
#pragma unroll
    for (int mt = 0; mt < 8; ++mt) {
      const short* kr = Ks + (mt * 16 + l15) * 64;
      bf16x8 ka0 = *(const bf16x8*)(kr + ((g ^ (l15 & 7)) * 8));
      bf16x8 ka1 = *(const bf16x8*)(kr + (((g + 4) ^ (l15 & 7)) * 8));
      f32x4 acc = {0.f, 0.f, 0.f, 0.f};
      acc = MFMA16(ka0, qb0, acc);
      acc = MFMA16(ka1, qb1, acc);
#pragma unroll
      for (int r = 0; r < 4; ++r) Sp[r] += exp2x(acc[r] * EXP2S);
    }
  }
  float S = Sp[0] + Sp[1] + Sp[2] + Sp[3];
  S += __shfl_xor(S, 16);
  S += __shfl_xor(S, 32);
  float iS = 1.0f / S;
  if (lane < 16) iSx[h * NN + nw + l15] = iS;

  // ---- pass B: attn store (non-temporal) + PV ----
  float* ab = attn + (size_t)h * NN * NN;
  f32x4 azc[4] = {};
  for (int mc = 0; mc < NN; mc += 128) {
    __syncthreads();
#pragma unroll
    for (int e = 0; e < 4; ++e) {
      int L = e * 256 + t, row = L >> 3, c = L & 7;
      GLL16(kb + (size_t)(mc + row) * DIM + ((c ^ (row & 7)) * 8), Ks + L * 8);
    }
#pragma unroll
    for (int e = 0; e < 4; ++e) {
      int L = e * 256 + t, row = L >> 4, c = L & 15;
      GLL16(vb + (size_t)row * NN + mc + ((c ^ (row & 15)) * 8), Vs + L * 8);
    }
    __syncthreads();
    float p[8][4];
#pragma unroll
    for (int mt = 0; mt < 8; ++mt) {
      const short* kr = Ks + (mt * 16 + l15) * 64;
      bf16x8 ka0 = *(const bf16x8*)(kr + ((g ^ (l15 & 7)) * 8));
      bf16x8 ka1 = *(const bf16x8*)(kr + (((g + 4) ^ (l15 & 7)) * 8));
      f32x4 acc = {0.f, 0.f, 0.f, 0.f};
      acc = MFMA16(ka0, qb0, acc);
      acc = MFMA16(ka1, qb1, acc);
      f32x4 pv;
#pragma unroll
      for (int r = 0; r < 4; ++r) { pv[r] = exp2x(acc[r] * EXP2S) * iS; p[mt][r] = pv[r]; }
      __builtin_nontemporal_store(pv,
          (f32x4*)(ab + (size_t)(nw + l15) * NN + mc + mt * 16 + g * 4));
    }
#pragma unroll
    for (int km = 0; km < 4; ++km) {
      unsigned int a0p = cvtpk(p[2*km][0],   p[2*km][1]);
      unsigned int a1p = cvtpk(p[2*km][2],   p[2*km][3]);
      unsigned int b0p = cvtpk(p[2*km+1][0], p[2*km+1][1]);
      unsigned int b1p = cvtpk(p[2*km+1][2], p[2*km+1][3]);
      int s0 = ((g & 1) * 2) * 16 + l15, s1 = s0 + 16;
      bool hi = g >= 2;
      unsigned int w0a = __shfl(a0p, s0), w0b = __shfl(b0p, s0);
      unsigned int w1a = __shfl(a1p, s0), w1b = __shfl(b1p, s0);
      unsigned int w2a = __shfl(a0p, s1), w2b = __shfl(b0p, s1);
      unsigned int w3a = __shfl(a1p, s1), w3b = __shfl(b1p, s1);
      union { u32x4 u; bf16x8 s; } pw;
      pw.u[0] = hi ? w0b : w0a; pw.u[1] = hi ? w1b : w1a;
      pw.u[2] = hi ? w2b : w2a; pw.u[3] = hi ? w3b : w3a;
#pragma unroll
      for (int ct = 0; ct < 4; ++ct) {
        bf16x8 pb = *(const bf16x8*)(Vs + (ct * 16 + l15) * 128 + (((km * 4 + g) ^ l15) * 8));
        azc[ct] = MFMA16(pw.s, pb, azc[ct]);
      }
    }
  }
#pragma unroll
  for (int ct = 0; ct < 4; ++ct)
#pragma unroll
    for (int r = 0; r < 4; ++r)
      zc[(size_t)(nw + g * 4 + r) * DIM + h * HD + ct * 16 + l15] = azc[ct][r];
}

// ---------------- v1 prescale: v1T[c][n] *= iS[n] (in place) ----------------
__global__ __launch_bounds__(256) void v1scale_kernel(
    short* __restrict__ v1T, const float* __restrict__ iSx) {
  int row = blockIdx.y;                 // 0..1023 (c index incl. head)
  int h = row >> 6;
  int n0 = (int)(blockIdx.x * 2048) + threadIdx.x * 8;
  short* p = v1T + (size_t)row * NN + n0;
  bf16x8 v = *(const bf16x8*)p;
  const float* isb = iSx + h * NN + n0;
  f32x4 i0 = ((const f32x4*)isb)[0];
  f32x4 i1 = ((const f32x4*)isb)[1];
  union { u32x4 u; bf16x8 s; } o;
  o.u[0] = cvtpk(bf2f(v[0]) * i0[0], bf2f(v[1]) * i0[1]);
  o.u[1] = cvtpk(bf2f(v[2]) * i0[2], bf2f(v[3]) * i0[3]);
  o.u[2] = cvtpk(bf2f(v[4]) * i1[0], bf2f(v[5]) * i1[1]);
  o.u[3] = cvtpk(bf2f(v[6]) * i1[2], bf2f(v[7]) * i1[3]);
  *(bf16x8*)p = o.s;
}

// ============ czr: round-8 structure, prescaled v1 (no iS loads) ============
__global__ __launch_bounds__(256, 4) void czr_kernel(
    const short* __restrict__ q, const short* __restrict__ k,
    const short* __restrict__ v1T, float* __restrict__ cz) {
  int bid = (int)(blockIdx.y * gridDim.x + blockIdx.x);
  int vid = (bid & 7) * 128 + (bid >> 3);
  int h = vid >> 6;
  int mblk = vid & 63;
  int t = threadIdx.x, wid = t >> 6, lane = t & 63;
  int g = lane >> 4, l15 = lane & 15;
  int mw = mblk * 64 + wid * 16;

  const short* kp = k + (size_t)(mw + l15) * DIM + h * HD + g * 8;
  bf16x8 kb0 = *(const bf16x8*)(kp);
  bf16x8 kb1 = *(const bf16x8*)(kp + 32);

  __shared__ __align__(16) short Qs[128 * 64];
  __shared__ __align__(16) short V1s[64 * 128];
  const short* qb = q + h * HD;
  const short* vb = v1T + (size_t)h * HD * NN;

  f32x4 acz[4] = {};
  for (int nc = 0; nc < NN; nc += 128) {
    __syncthreads();
#pragma unroll
    for (int e = 0; e < 4; ++e) {
      int L = e * 256 + t, row = L >> 3, c = L & 7;
      GLL16(qb + (size_t)(nc + row) * DIM + ((c ^ (row & 7)) * 8), Qs + L * 8);
    }
#pragma unroll
    for (int e = 0; e < 4; ++e) {
      int L = e * 256 + t, row = L >> 4, c = L & 15;
      GLL16(vb + (size_t)row * NN + nc + ((c ^ (row & 15)) * 8), V1s + L * 8);
    }
    __syncthreads();
    float p[8][4];
#pragma unroll
    for (int nt = 0; nt < 8; ++nt) {
      const short* qr = Qs + (nt * 16 + l15) * 64;
      bf16x8 qa0 = *(const bf16x8*)(qr + ((g ^ (l15 & 7)) * 8));
      bf16x8 qa1 = *(const bf16x8*)(qr + (((g + 4) ^ (l15 & 7)) * 8));
      f32x4 acc = {0.f, 0.f, 0.f, 0.f};
      acc = MFMA16(qa0, kb0, acc);
      acc = MFMA16(qa1, kb1, acc);
#pragma unroll
      for (int r = 0; r < 4; ++r) p[nt][r] = exp2x(acc[r] * EXP2S);
    }
#pragma unroll
    for (int kn = 0; kn < 4; ++kn) {
      unsigned int a0p = cvtpk(p[2*kn][0],   p[2*kn][1]);
      unsigned int a1p = cvtpk(p[2*kn][2],   p[2*kn][3]);
      unsigned int b0p = cvtpk(p[2*kn+1][0], p[2*kn+1][1]);
      unsigned int b1p = cvtpk(p[2*kn+1][2], p[2*kn+1][3]);
      int s0 = ((g & 1) * 2) * 16 + l15, s1 = s0 + 16;
      bool hi = g >= 2;
      unsigned int w0a = __shfl(a0p, s0), w0b = __shfl(b0p, s0);
      unsigned int w1a = __shfl(a1p, s0), w1b = __shfl(b1p, s0);
      unsigned int w2a = __shfl(a0p, s1), w2b = __shfl(b0p, s1);
      unsigned int w3a = __shfl(a1p, s1), w3b = __shfl(b1p, s1);
      union { u32x4 u; bf16x8 s; } pw;
      pw.u[0] = hi ? w0b : w0a; pw.u[1] = hi ? w1b : w1a;
      pw.u[2] = hi ? w2b : w2a; pw.u[3] = hi ? w3b : w3a;
#pragma unroll
      for (int ct = 0; ct < 4; ++ct) {
        bf16x8 pb = *(const bf16x8*)(V1s + (ct * 16 + l15) * 128 + (((kn * 4 + g) ^ l15) * 8));
        acz[ct] = MFMA16(pw.s, pb, acz[ct]);
      }
    }
  }
#pragma unroll
  for (int ct = 0; ct < 4; ++ct)
#pragma unroll
    for (int r = 0; r < 4; ++r)
      cz[(size_t)(mw + g * 4 + r) * DIM + h * HD + ct * 16 + l15] = acz[ct][r];
}

extern "C" void kernel_launch(void* const* d_in, const int* in_sizes, int n_in,
                              void* d_out, int out_size, void* d_ws, size_t ws_size,
                              hipStream_t stream) {
  static const int expect[14] = {4194304, 4194304, 1048576, 1024, 1048576, 1024,
                                 1048576, 1024, 1048576, 1024, 1024, 1024, 1024, 1024};
  if (n_in != 14) return;
  for (int i = 0; i < 14; ++i) if (in_sizes[i] != expect[i]) return;
  if (out_size != 2 * NN * DIM + (size_t)HEADS * NN * NN) return;

  const float* z1  = (const float*)d_in[0];
  const float* z2  = (const float*)d_in[1];
  const float* wq  = (const float*)d_in[2];
  const float* bq  = (const float*)d_in[3];
  const float* wk  = (const float*)d_in[4];
  const float* bk  = (const float*)d_in[5];
  const float* wv1 = (const float*)d_in[6];
  const float* bv1 = (const float*)d_in[7];
  const float* wv2 = (const float*)d_in[8];
  const float* bv2 = (const float*)d_in[9];
  const float* g1  = (const float*)d_in[10];
  const float* be1 = (const float*)d_in[11];
  const float* g2  = (const float*)d_in[12];
  const float* be2 = (const float*)d_in[13];

  float* out  = (float*)d_out;
  float* zc   = out;
  float* cz   = out + (size_t)NN * DIM;
  float* attn = out + 2 * (size_t)NN * DIM;

  short* n1 = (short*)zc;
  short* n2 = (short*)cz;
  short* wb = (short*)attn;

  char* ws = (char*)d_ws;
  const size_t MB = 1024 * 1024;
  short* q   = (short*)(ws);
  short* k   = (short*)(ws + 8 * MB);
  short* vT  = (short*)(ws + 16 * MB);
  short* v1T = (short*)(ws + 24 * MB);
  float* iSx = (float*)(ws + 32 * MB);

  ln_kernel<<<dim3(NN, 2), 256, 0, stream>>>(z1, z2, g1, be1, g2, be2, n1, n2);
  cvt_w_kernel<<<dim3(DIM * DIM / 1024, 4), 256, 0, stream>>>(wq, wk, wv1, wv2, wb);
  proj_kernel<<<dim3(DIM / 128, NN / 128, 4), 256, 0, stream>>>(n1, n2, wb, bq, bk, bv1, bv2, q, k, vT, v1T);
  p2zc_kernel<<<dim3(NN / 64, HEADS), 256, 0, stream>>>(q, k, vT, attn, zc, iSx);
  v1scale_kernel<<<dim3(NN / 2048, DIM), 256, 0, stream>>>(v1T, iSx);
  czr_kernel<<<dim3(NN / 64, HEADS), 256, 0, stream>>>(q, k, v1T, cz);
}

// Round 16
// 533.324 us; speedup vs baseline: 1.0428x; 1.0046x over previous
//
#include <hip/hip_runtime.h>

#define NN 4096
#define DIM 1024
#define HEADS 16
#define HD 64
#define SCALE 0.03125f
// SCALE * log2(e): exp(s*SCALE) == exp2(s*EXP2S)
#define EXP2S 0.04508422002778011f

typedef __attribute__((ext_vector_type(8))) short bf16x8;
typedef __attribute__((ext_vector_type(4))) short short4v;
typedef __attribute__((ext_vector_type(4))) float f32x4;
typedef __attribute__((ext_vector_type(4))) unsigned int u32x4;

__device__ __forceinline__ short f2bf(float f) {
  unsigned int x = __float_as_uint(f);
  unsigned int r = x + 0x7FFFu + ((x >> 16) & 1u);
  return (short)(r >> 16);
}
__device__ __forceinline__ float bf2f(short s) {
  return __uint_as_float(((unsigned int)(unsigned short)s) << 16);
}
// packed f32x2 -> bf16x2 (RNE), single instruction
__device__ __forceinline__ unsigned int cvtpk(float a, float b) {
  unsigned int r;
  asm("v_cvt_pk_bf16_f32 %0, %1, %2" : "=v"(r) : "v"(a), "v"(b));
  return r;
}
// 2^x via v_exp_f32
__device__ __forceinline__ float exp2x(float x) {
  float r;
  asm("v_exp_f32 %0, %1" : "=v"(r) : "v"(x));
  return r;
}

#define GLL16(gp, lp) __builtin_amdgcn_global_load_lds( \
    (const __attribute__((address_space(1))) unsigned int*)(gp), \
    (__attribute__((address_space(3))) unsigned int*)(lp), 16, 0, 0)

#define MFMA16(a, b, c) __builtin_amdgcn_mfma_f32_16x16x32_bf16(a, b, c, 0, 0, 0)

// ---------------- LayerNorm: f32 z -> bf16 normalized ----------------
__global__ __launch_bounds__(256) void ln_kernel(
    const float* __restrict__ z1, const float* __restrict__ z2,
    const float* __restrict__ g1, const float* __restrict__ be1,
    const float* __restrict__ g2, const float* __restrict__ be2,
    short* __restrict__ n1, short* __restrict__ n2) {
  int row = blockIdx.x;
  int which = blockIdx.y;
  const float* src = (which ? z2 : z1) + (size_t)row * DIM;
  const float* g  = which ? g2 : g1;
  const float* be = which ? be2 : be1;
  short* dst = (which ? n2 : n1) + (size_t)row * DIM;
  int t = threadIdx.x;
  float4 v = ((const float4*)src)[t];
  float s  = v.x + v.y + v.z + v.w;
  float s2 = v.x*v.x + v.y*v.y + v.z*v.z + v.w*v.w;
#pragma unroll
  for (int off = 32; off >= 1; off >>= 1) {
    s  += __shfl_xor(s, off);
    s2 += __shfl_xor(s2, off);
  }
  __shared__ __align__(16) float ls[8];
  int wid = t >> 6;
  if ((t & 63) == 0) { ls[wid] = s; ls[wid + 4] = s2; }
  __syncthreads();
  s  = ls[0] + ls[1] + ls[2] + ls[3];
  s2 = ls[4] + ls[5] + ls[6] + ls[7];
  float mu = s * (1.0f / DIM);
  float var = s2 * (1.0f / DIM) - mu * mu;
  float rs = rsqrtf(var + 1e-5f);
  float4 gv = ((const float4*)g)[t];
  float4 bv = ((const float4*)be)[t];
  short4v o;
  o.x = f2bf((v.x - mu) * rs * gv.x + bv.x);
  o.y = f2bf((v.y - mu) * rs * gv.y + bv.y);
  o.z = f2bf((v.z - mu) * rs * gv.z + bv.z);
  o.w = f2bf((v.w - mu) * rs * gv.w + bv.w);
  ((short4v*)dst)[t] = o;
}

// ---------------- weights f32 -> bf16 ----------------
__global__ __launch_bounds__(256) void cvt_w_kernel(
    const float* __restrict__ w0, const float* __restrict__ w1,
    const float* __restrict__ w2, const float* __restrict__ w3,
    short* __restrict__ wb) {
  int y = blockIdx.y;
  const float* src = (y == 0) ? w0 : (y == 1) ? w1 : (y == 2) ? w2 : w3;
  size_t i = (size_t)blockIdx.x * 256 + threadIdx.x;
  float4 v = ((const float4*)src)[i];
  short4v o;
  o.x = f2bf(v.x); o.y = f2bf(v.y); o.z = f2bf(v.z); o.w = f2bf(v.w);
  ((short4v*)(wb + (size_t)y * DIM * DIM))[i] = o;
}

// ---------------- batched projection GEMM (round-5-verified, BK=32) ----------------
__global__ __launch_bounds__(256) void proj_kernel(
    const short* __restrict__ n1, const short* __restrict__ n2,
    const short* __restrict__ wb,
    const float* __restrict__ bq, const float* __restrict__ bk,
    const float* __restrict__ bv1, const float* __restrict__ bv2,
    short* __restrict__ q, short* __restrict__ k,
    short* __restrict__ vT, short* __restrict__ v1T) {
  int z = blockIdx.z;
  const short* A = (z == 1 || z == 2) ? n2 : n1;
  const short* B = wb + (size_t)z * DIM * DIM;
  const float* bias = (z == 0) ? bq : (z == 1) ? bk : (z == 2) ? bv1 : bv2;
  int i0 = blockIdx.y * 128, j0 = blockIdx.x * 128;
  __shared__ __align__(16) short As[128 * 32];
  __shared__ __align__(16) short Bs[128 * 32];
  int t = threadIdx.x;
  int wid = t >> 6, lane = t & 63, g = lane >> 4, l15 = lane & 15;
  int wi = (wid >> 1) * 64, wj = (wid & 1) * 64;
  f32x4 acc[4][4] = {};
  for (int kt = 0; kt < DIM; kt += 32) {
    __syncthreads();
#pragma unroll
    for (int e = 0; e < 2; ++e) {
      int lin = e * 256 + t;
      int row = lin >> 2, kc = (lin & 3) * 8;
      GLL16(A + (size_t)(i0 + row) * DIM + kt + kc, As + lin * 8);
      GLL16(B + (size_t)(j0 + row) * DIM + kt + kc, Bs + lin * 8);
    }
    __syncthreads();
    bf16x8 af[4], bfr[4];
#pragma unroll
    for (int it = 0; it < 4; ++it)
      af[it] = *(const bf16x8*)(As + (wi + it * 16 + l15) * 32 + g * 8);
#pragma unroll
    for (int jt = 0; jt < 4; ++jt)
      bfr[jt] = *(const bf16x8*)(Bs + (wj + jt * 16 + l15) * 32 + g * 8);
#pragma unroll
    for (int it = 0; it < 4; ++it)
#pragma unroll
      for (int jt = 0; jt < 4; ++jt)
        acc[it][jt] = MFMA16(af[it], bfr[jt], acc[it][jt]);
  }
  if (z < 2) {
    short* out = (z == 0) ? q : k;
#pragma unroll
    for (int jt = 0; jt < 4; ++jt) {
      int j = j0 + wj + jt * 16 + l15;
      float bj = bias[j];
#pragma unroll
      for (int it = 0; it < 4; ++it) {
        int i = i0 + wi + it * 16 + g * 4;
#pragma unroll
        for (int r = 0; r < 4; ++r)
          out[(size_t)(i + r) * DIM + j] = f2bf(acc[it][jt][r] + bj);
      }
    }
  } else {
    short* out = (z == 2) ? vT : v1T;
#pragma unroll
    for (int jt = 0; jt < 4; ++jt) {
      int j = j0 + wj + jt * 16 + l15;
      float bj = bias[j];
#pragma unroll
      for (int it = 0; it < 4; ++it) {
        int i = i0 + wi + it * 16 + g * 4;
        short4v o;
#pragma unroll
        for (int r = 0; r < 4; ++r) o[r] = f2bf(acc[it][jt][r] + bj);
        *(short4v*)(out + (size_t)j * NN + i) = o;
      }
    }
  }
}

// ============ p2zc: S^T formulation; pass A = 2-phase double-buffered (Ks/Vs) ============
__global__ __launch_bounds__(256, 4) void p2zc_kernel(
    const short* __restrict__ q, const short* __restrict__ k,
    const short* __restrict__ vT, float* __restrict__ attn,
    float* __restrict__ zc, float* __restrict__ iSx) {
  int bid = (int)(blockIdx.y * gridDim.x + blockIdx.x);
  int vid = (bid & 7) * 128 + (bid >> 3);   // XCD-contiguous remap (1024 % 8 == 0)
  int h = vid >> 6;
  int nblk = vid & 63;
  int t = threadIdx.x, wid = t >> 6, lane = t & 63;
  int g = lane >> 4, l15 = lane & 15;
  int nw = nblk * 64 + wid * 16;

  const short* qp = q + (size_t)(nw + l15) * DIM + h * HD + g * 8;
  bf16x8 qb0 = *(const bf16x8*)(qp);
  bf16x8 qb1 = *(const bf16x8*)(qp + 32);

  __shared__ __align__(16) short Ks[128 * 64];   // 16 KB, xor-swizzled chunks
  __shared__ __align__(16) short Vs[64 * 128];   // 16 KB; pass A: K double-buffer; pass B: V tile
  const short* kb = k + h * HD;
  const short* vb = vT + (size_t)h * HD * NN;

  // ---- pass A: row sums of exp — 2-phase pipeline, counted vmcnt ----
  f32x4 Sp = {0.f, 0.f, 0.f, 0.f};
  {
    // prologue: stage chunk 0 into Ks
#pragma unroll
    for (int e = 0; e < 4; ++e) {
      int L = e * 256 + t, row = L >> 3, c = L & 7;
      GLL16(kb + (size_t)row * DIM + ((c ^ (row & 7)) * 8), Ks + L * 8);
    }
    for (int ci = 0; ci < 32; ++ci) {
      short* cur = (ci & 1) ? (short*)Vs : (short*)Ks;
      short* nxt = (ci & 1) ? (short*)Ks : (short*)Vs;
      if (ci < 31) {
        int mc1 = (ci + 1) * 128;
#pragma unroll
        for (int e = 0; e < 4; ++e) {
          int L = e * 256 + t, row = L >> 3, c = L & 7;
          GLL16(kb + (size_t)(mc1 + row) * DIM + ((c ^ (row & 7)) * 8), nxt + L * 8);
        }
        asm volatile("s_waitcnt vmcnt(4)" ::: "memory");   // chunk-ci loads retired
      } else {
        asm volatile("s_waitcnt vmcnt(0)" ::: "memory");
      }
      __builtin_amdgcn_s_barrier();          // all waves' chunk-ci data resident
      __builtin_amdgcn_sched_barrier(0);
#pragma unroll
      for (int mt = 0; mt < 8; ++mt) {
        const short* kr = cur + (mt * 16 + l15) * 64;
        bf16x8 ka0 = *(const bf16x8*)(kr + ((g ^ (l15 & 7)) * 8));
        bf16x8 ka1 = *(const bf16x8*)(kr + (((g + 4) ^ (l15 & 7)) * 8));
        f32x4 acc = {0.f, 0.f, 0.f, 0.f};
        acc = MFMA16(ka0, qb0, acc);
        acc = MFMA16(ka1, qb1, acc);
#pragma unroll
        for (int r = 0; r < 4; ++r) Sp[r] += exp2x(acc[r] * EXP2S);
      }
      __builtin_amdgcn_s_barrier();          // reads done before cur is re-staged (ci+2)
      __builtin_amdgcn_sched_barrier(0);
    }
  }
  float S = Sp[0] + Sp[1] + Sp[2] + Sp[3];
  S += __shfl_xor(S, 16);
  S += __shfl_xor(S, 32);
  float iS = 1.0f / S;
  if (lane < 16) iSx[h * NN + nw + l15] = iS;

  // ---- pass B: attn store (non-temporal) + PV ----
  float* ab = attn + (size_t)h * NN * NN;
  f32x4 azc[4] = {};
  for (int mc = 0; mc < NN; mc += 128) {
    __syncthreads();
#pragma unroll
    for (int e = 0; e < 4; ++e) {
      int L = e * 256 + t, row = L >> 3, c = L & 7;
      GLL16(kb + (size_t)(mc + row) * DIM + ((c ^ (row & 7)) * 8), Ks + L * 8);
    }
#pragma unroll
    for (int e = 0; e < 4; ++e) {
      int L = e * 256 + t, row = L >> 4, c = L & 15;
      GLL16(vb + (size_t)row * NN + mc + ((c ^ (row & 15)) * 8), Vs + L * 8);
    }
    __syncthreads();
    float p[8][4];
#pragma unroll
    for (int mt = 0; mt < 8; ++mt) {
      const short* kr = Ks + (mt * 16 + l15) * 64;
      bf16x8 ka0 = *(const bf16x8*)(kr + ((g ^ (l15 & 7)) * 8));
      bf16x8 ka1 = *(const bf16x8*)(kr + (((g + 4) ^ (l15 & 7)) * 8));
      f32x4 acc = {0.f, 0.f, 0.f, 0.f};
      acc = MFMA16(ka0, qb0, acc);
      acc = MFMA16(ka1, qb1, acc);
      f32x4 pv;
#pragma unroll
      for (int r = 0; r < 4; ++r) { pv[r] = exp2x(acc[r] * EXP2S) * iS; p[mt][r] = pv[r]; }
      __builtin_nontemporal_store(pv,
          (f32x4*)(ab + (size_t)(nw + l15) * NN + mc + mt * 16 + g * 4));
    }
#pragma unroll
    for (int km = 0; km < 4; ++km) {
      unsigned int a0p = cvtpk(p[2*km][0],   p[2*km][1]);
      unsigned int a1p = cvtpk(p[2*km][2],   p[2*km][3]);
      unsigned int b0p = cvtpk(p[2*km+1][0], p[2*km+1][1]);
      unsigned int b1p = cvtpk(p[2*km+1][2], p[2*km+1][3]);
      int s0 = ((g & 1) * 2) * 16 + l15, s1 = s0 + 16;
      bool hi = g >= 2;
      unsigned int w0a = __shfl(a0p, s0), w0b = __shfl(b0p, s0);
      unsigned int w1a = __shfl(a1p, s0), w1b = __shfl(b1p, s0);
      unsigned int w2a = __shfl(a0p, s1), w2b = __shfl(b0p, s1);
      unsigned int w3a = __shfl(a1p, s1), w3b = __shfl(b1p, s1);
      union { u32x4 u; bf16x8 s; } pw;
      pw.u[0] = hi ? w0b : w0a; pw.u[1] = hi ? w1b : w1a;
      pw.u[2] = hi ? w2b : w2a; pw.u[3] = hi ? w3b : w3a;
#pragma unroll
      for (int ct = 0; ct < 4; ++ct) {
        bf16x8 pb = *(const bf16x8*)(Vs + (ct * 16 + l15) * 128 + (((km * 4 + g) ^ l15) * 8));
        azc[ct] = MFMA16(pw.s, pb, azc[ct]);
      }
    }
  }
#pragma unroll
  for (int ct = 0; ct < 4; ++ct)
#pragma unroll
    for (int r = 0; r < 4; ++r)
      zc[(size_t)(nw + g * 4 + r) * DIM + h * HD + ct * 16 + l15] = azc[ct][r];
}

// ---------------- v1 prescale: v1T[c][n] *= iS[n] (in place) ----------------
__global__ __launch_bounds__(256) void v1scale_kernel(
    short* __restrict__ v1T, const float* __restrict__ iSx) {
  int row = blockIdx.y;                 // 0..1023 (c index incl. head)
  int h = row >> 6;
  int n0 = (int)(blockIdx.x * 2048) + threadIdx.x * 8;
  short* p = v1T + (size_t)row * NN + n0;
  bf16x8 v = *(const bf16x8*)p;
  const float* isb = iSx + h * NN + n0;
  f32x4 i0 = ((const f32x4*)isb)[0];
  f32x4 i1 = ((const f32x4*)isb)[1];
  union { u32x4 u; bf16x8 s; } o;
  o.u[0] = cvtpk(bf2f(v[0]) * i0[0], bf2f(v[1]) * i0[1]);
  o.u[1] = cvtpk(bf2f(v[2]) * i0[2], bf2f(v[3]) * i0[3]);
  o.u[2] = cvtpk(bf2f(v[4]) * i1[0], bf2f(v[5]) * i1[1]);
  o.u[3] = cvtpk(bf2f(v[6]) * i1[2], bf2f(v[7]) * i1[3]);
  *(bf16x8*)p = o.s;
}

// ============ czr: round-8 structure, prescaled v1 (no iS loads) ============
__global__ __launch_bounds__(256, 4) void czr_kernel(
    const short* __restrict__ q, const short* __restrict__ k,
    const short* __restrict__ v1T, float* __restrict__ cz) {
  int bid = (int)(blockIdx.y * gridDim.x + blockIdx.x);
  int vid = (bid & 7) * 128 + (bid >> 3);
  int h = vid >> 6;
  int mblk = vid & 63;
  int t = threadIdx.x, wid = t >> 6, lane = t & 63;
  int g = lane >> 4, l15 = lane & 15;
  int mw = mblk * 64 + wid * 16;

  const short* kp = k + (size_t)(mw + l15) * DIM + h * HD + g * 8;
  bf16x8 kb0 = *(const bf16x8*)(kp);
  bf16x8 kb1 = *(const bf16x8*)(kp + 32);

  __shared__ __align__(16) short Qs[128 * 64];
  __shared__ __align__(16) short V1s[64 * 128];
  const short* qb = q + h * HD;
  const short* vb = v1T + (size_t)h * HD * NN;

  f32x4 acz[4] = {};
  for (int nc = 0; nc < NN; nc += 128) {
    __syncthreads();
#pragma unroll
    for (int e = 0; e < 4; ++e) {
      int L = e * 256 + t, row = L >> 3, c = L & 7;
      GLL16(qb + (size_t)(nc + row) * DIM + ((c ^ (row & 7)) * 8), Qs + L * 8);
    }
#pragma unroll
    for (int e = 0; e < 4; ++e) {
      int L = e * 256 + t, row = L >> 4, c = L & 15;
      GLL16(vb + (size_t)row * NN + nc + ((c ^ (row & 15)) * 8), V1s + L * 8);
    }
    __syncthreads();
    float p[8][4];
#pragma unroll
    for (int nt = 0; nt < 8; ++nt) {
      const short* qr = Qs + (nt * 16 + l15) * 64;
      bf16x8 qa0 = *(const bf16x8*)(qr + ((g ^ (l15 & 7)) * 8));
      bf16x8 qa1 = *(const bf16x8*)(qr + (((g + 4) ^ (l15 & 7)) * 8));
      f32x4 acc = {0.f, 0.f, 0.f, 0.f};
      acc = MFMA16(qa0, kb0, acc);
      acc = MFMA16(qa1, kb1, acc);
#pragma unroll
      for (int r = 0; r < 4; ++r) p[nt][r] = exp2x(acc[r] * EXP2S);
    }
#pragma unroll
    for (int kn = 0; kn < 4; ++kn) {
      unsigned int a0p = cvtpk(p[2*kn][0],   p[2*kn][1]);
      unsigned int a1p = cvtpk(p[2*kn][2],   p[2*kn][3]);
      unsigned int b0p = cvtpk(p[2*kn+1][0], p[2*kn+1][1]);
      unsigned int b1p = cvtpk(p[2*kn+1][2], p[2*kn+1][3]);
      int s0 = ((g & 1) * 2) * 16 + l15, s1 = s0 + 16;
      bool hi = g >= 2;
      unsigned int w0a = __shfl(a0p, s0), w0b = __shfl(b0p, s0);
      unsigned int w1a = __shfl(a1p, s0), w1b = __shfl(b1p, s0);
      unsigned int w2a = __shfl(a0p, s1), w2b = __shfl(b0p, s1);
      unsigned int w3a = __shfl(a1p, s1), w3b = __shfl(b1p, s1);
      union { u32x4 u; bf16x8 s; } pw;
      pw.u[0] = hi ? w0b : w0a; pw.u[1] = hi ? w1b : w1a;
      pw.u[2] = hi ? w2b : w2a; pw.u[3] = hi ? w3b : w3a;
#pragma unroll
      for (int ct = 0; ct < 4; ++ct) {
        bf16x8 pb = *(const bf16x8*)(V1s + (ct * 16 + l15) * 128 + (((kn * 4 + g) ^ l15) * 8));
        acz[ct] = MFMA16(pw.s, pb, acz[ct]);
      }
    }
  }
#pragma unroll
  for (int ct = 0; ct < 4; ++ct)
#pragma unroll
    for (int r = 0; r < 4; ++r)
      cz[(size_t)(mw + g * 4 + r) * DIM + h * HD + ct * 16 + l15] = acz[ct][r];
}

extern "C" void kernel_launch(void* const* d_in, const int* in_sizes, int n_in,
                              void* d_out, int out_size, void* d_ws, size_t ws_size,
                              hipStream_t stream) {
  static const int expect[14] = {4194304, 4194304, 1048576, 1024, 1048576, 1024,
                                 1048576, 1024, 1048576, 1024, 1024, 1024, 1024, 1024};
  if (n_in != 14) return;
  for (int i = 0; i < 14; ++i) if (in_sizes[i] != expect[i]) return;
  if (out_size != 2 * NN * DIM + (size_t)HEADS * NN * NN) return;

  const float* z1  = (const float*)d_in[0];
  const float* z2  = (const float*)d_in[1];
  const float* wq  = (const float*)d_in[2];
  const float* bq  = (const float*)d_in[3];
  const float* wk  = (const float*)d_in[4];
  const float* bk  = (const float*)d_in[5];
  const float* wv1 = (const float*)d_in[6];
  const float* bv1 = (const float*)d_in[7];
  const float* wv2 = (const float*)d_in[8];
  const float* bv2 = (const float*)d_in[9];
  const float* g1  = (const float*)d_in[10];
  const float* be1 = (const float*)d_in[11];
  const float* g2  = (const float*)d_in[12];
  const float* be2 = (const float*)d_in[13];

  float* out  = (float*)d_out;
  float* zc   = out;
  float* cz   = out + (size_t)NN * DIM;
  float* attn = out + 2 * (size_t)NN * DIM;

  short* n1 = (short*)zc;
  short* n2 = (short*)cz;
  short* wb = (short*)attn;

  char* ws = (char*)d_ws;
  const size_t MB = 1024 * 1024;
  short* q   = (short*)(ws);
  short* k   = (short*)(ws + 8 * MB);
  short* vT  = (short*)(ws + 16 * MB);
  short* v1T = (short*)(ws + 24 * MB);
  float* iSx = (float*)(ws + 32 * MB);

  ln_kernel<<<dim3(NN, 2), 256, 0, stream>>>(z1, z2, g1, be1, g2, be2, n1, n2);
  cvt_w_kernel<<<dim3(DIM * DIM / 1024, 4), 256, 0, stream>>>(wq, wk, wv1, wv2, wb);
  proj_kernel<<<dim3(DIM / 128, NN / 128, 4), 256, 0, stream>>>(n1, n2, wb, bq, bk, bv1, bv2, q, k, vT, v1T);
  p2zc_kernel<<<dim3(NN / 64, HEADS), 256, 0, stream>>>(q, k, vT, attn, zc, iSx);
  v1scale_kernel<<<dim3(NN / 2048, DIM), 256, 0, stream>>>(v1T, iSx);
  czr_kernel<<<dim3(NN / 64, HEADS), 256, 0, stream>>>(q, k, v1T, cz);
}